// Round 1
// baseline (387.109 us; speedup 1.0000x reference)
//
#include <hip/hip_runtime.h>
#include <stdint.h>

// TripletLoss: reproduce JAX reference exactly, including threefry2x32 Gumbel noise.
// E=8192 edges, N=2048 nodes, K=8 clusters, L=16 keypoints, top-400 of E^2 Gumbel-perturbed logw.
// Key insight: only valid (pos_i, neg_j, same-anchor, w>0) pairs are finite (~4k of 67M);
// top-k over the full matrix == top-k over the finite candidates (padded with -inf -> ok=false).

#define E_CONST 8192
#define N_CONST 2048
#define K_CONST 8
#define L_CONST 16
#define MAXS 400
#define EPS_F 1e-9f

// JAX >= 0.4.30 default: jax_threefry_partitionable = True.
// 1: per-element counts (0, flat_idx), bits = o0 ^ o1.
// 0: legacy split-halves: pair (i, i+2^25), word0 for first half / word1 for second.
#define JAX_PARTITIONABLE 1

struct Cand { float val; uint32_t pack; };

// ---- ws layout (bytes) ----
// 0      : clst   int32[N]          (8192)
// 8192   : header uint32[16]        {mask, n_pos, n_neg, n_cand, ...}
// 8256   : anchor int32[E]          (32768)
// 41024  : bc     float[E]          (32768)
// 73792  : pos_list int32[E]        (32768)
// 106560 : neg_list int32[E]        (32768)
// 139328 : cand   Cand[CAP]

__device__ __forceinline__ uint2 threefry2x32_42(uint32_t x0, uint32_t x1) {
    // key = (0, 42) from jax.random.key(42)
    const uint32_t ks0 = 0u, ks1 = 42u;
    const uint32_t ks2 = ks0 ^ ks1 ^ 0x1BD11BDAu;
    const uint32_t ks[3] = {ks0, ks1, ks2};
    const int R[2][4] = {{13, 15, 26, 6}, {17, 29, 16, 24}};
    x0 += ks0; x1 += ks1;
#pragma unroll
    for (int g = 0; g < 5; ++g) {
        const int* r = R[g & 1];
#pragma unroll
        for (int q = 0; q < 4; ++q) {
            x0 += x1;
            x1 = (x1 << r[q]) | (x1 >> (32 - r[q]));
            x1 ^= x0;
        }
        x0 += ks[(g + 1) % 3];
        x1 += ks[(g + 2) % 3] + (uint32_t)(g + 1);
    }
    return make_uint2(x0, x1);
}

__device__ __forceinline__ float gumbel_at(uint32_t idx) {
    uint32_t bits;
#if JAX_PARTITIONABLE
    uint2 o = threefry2x32_42(0u, idx);
    bits = o.x ^ o.y;
#else
    const uint32_t half = 1u << 25;  // E*E/2
    if (idx < half) { uint2 o = threefry2x32_42(idx, idx + half); bits = o.x; }
    else            { uint2 o = threefry2x32_42(idx - half, idx); bits = o.y; }
#endif
    // jax uniform: bitcast((bits>>9)|0x3F800000) - 1.0, in [0,1)
    float u = __uint_as_float((bits >> 9) | 0x3F800000u) - 1.0f;
    return -logf(-logf(u + EPS_F) + EPS_F);
}

__global__ void k_prep(const float* __restrict__ clusters, const int* __restrict__ keypts,
                       int* __restrict__ clst, uint32_t* __restrict__ header) {
    int tid = threadIdx.x;
    for (int n = tid; n < N_CONST; n += blockDim.x) {
        const float* row = clusters + n * K_CONST;
        float best = row[0]; int bi = 0;
#pragma unroll
        for (int k = 1; k < K_CONST; ++k) {
            float v = row[k];
            if (v > best) { best = v; bi = k; }  // first-max, matches jnp.argmax
        }
        clst[n] = bi;
    }
    __syncthreads();
    if (tid == 0) {
        uint32_t m = 0;
        for (int l = 0; l < L_CONST; ++l) m |= 1u << clst[keypts[l]];
        header[0] = m;
        header[1] = 0;  // n_pos
        header[2] = 0;  // n_neg
        header[3] = 0;  // n_cand
    }
}

__global__ void k_edges(const float* __restrict__ clusters, const int* __restrict__ edges,
                        const int* __restrict__ clst, uint32_t* __restrict__ header,
                        int* __restrict__ anchor, float* __restrict__ bc,
                        int* __restrict__ pos_list, int* __restrict__ neg_list) {
    int e = blockIdx.x * blockDim.x + threadIdx.x;
    if (e >= E_CONST) return;
    int e0 = edges[2 * e], e1 = edges[2 * e + 1];
    int c0 = clst[e0], c1 = clst[e1];
    uint32_t m = header[0];
    bool sel = (((m >> c0) & 1u) | ((m >> c1) & 1u)) != 0u;
    const float* r0 = clusters + e0 * K_CONST;
    const float* r1 = clusters + e1 * K_CONST;
    float s = 0.f;
#pragma unroll
    for (int k = 0; k < K_CONST; ++k) s += sqrtf(r0[k] * r1[k]);  // sequential k, matches reduce order
    anchor[e] = e0;
    bc[e] = s;
    if (sel) {
        if (c0 == c1) { int p = atomicAdd((int*)&header[1], 1); pos_list[p] = e; }
        else          { int p = atomicAdd((int*)&header[2], 1); neg_list[p] = e; }
    }
}

__global__ void k_pairs(const int* __restrict__ anchor, const float* __restrict__ bc,
                        const int* __restrict__ pos_list, const int* __restrict__ neg_list,
                        uint32_t* __restrict__ header, Cand* __restrict__ cand, int cap) {
    int n_pos = ((int*)header)[1];
    int n_neg = ((int*)header)[2];
    long long total = (long long)n_pos * (long long)n_neg;
    long long stride = (long long)gridDim.x * blockDim.x;
    for (long long t = (long long)blockIdx.x * blockDim.x + threadIdx.x; t < total; t += stride) {
        int ip = (int)(t / n_neg);
        int jn = (int)(t - (long long)ip * n_neg);
        int i = pos_list[ip];
        int j = neg_list[jn];
        if (anchor[i] != anchor[j]) continue;
        float w = 1.0f - 0.5f * (bc[i] + bc[j]);
        if (!(w > 0.0f)) continue;  // valid & (w>0); else logw = -inf -> never in finite top-k
        uint32_t idx = (uint32_t)i * (uint32_t)E_CONST + (uint32_t)j;
        float val = logf(fmaxf(w, EPS_F)) + gumbel_at(idx);
        int slot = atomicAdd((int*)&header[3], 1);
        if (slot < cap) {
            cand[slot].val = val;
            cand[slot].pack = ((uint32_t)i << 16) | (uint32_t)j;
        }
    }
}

__device__ __forceinline__ uint32_t sortable_key(float f) {
    uint32_t b = __float_as_uint(f);
    return (b & 0x80000000u) ? ~b : (b | 0x80000000u);
}

__global__ void k_topk(const float* __restrict__ probas, const uint32_t* __restrict__ header,
                       const Cand* __restrict__ cand, int cap, float* __restrict__ out) {
    __shared__ int s_cnt;
    __shared__ float s_sum;
    int M = ((const int*)header)[3];
    if (M > cap) M = cap;
    int tid = threadIdx.x;

    uint32_t thr = 0;
    if (M > MAXS) {
        // binary search: max t such that count(key >= t) >= MAXS  -> t = 400th-largest key
        uint32_t lo = 0, hi = 0xFFFFFFFFu;
        while (lo < hi) {
            uint32_t mid = (uint32_t)(((uint64_t)lo + (uint64_t)hi + 1ull) >> 1);
            if (tid == 0) s_cnt = 0;
            __syncthreads();
            int c = 0;
            for (int t = tid; t < M; t += blockDim.x)
                if (sortable_key(cand[t].val) >= mid) c++;
            atomicAdd(&s_cnt, c);
            __syncthreads();
            int total = s_cnt;
            __syncthreads();
            if (total >= MAXS) lo = mid; else hi = mid - 1;
        }
        thr = lo;
    }

    if (tid == 0) { s_cnt = 0; s_sum = 0.f; }
    __syncthreads();
    float mysum = 0.f;
    int myc = 0;
    for (int t = tid; t < M; t += blockDim.x) {
        if (M <= MAXS || sortable_key(cand[t].val) >= thr) {
            uint32_t pk = cand[t].pack;
            int i = (int)(pk >> 16), j = (int)(pk & 0xFFFFu);
            float pi = probas[i], pj = probas[j];
            mysum += logf(pi / (pi + pj));
            myc++;
        }
    }
    atomicAdd(&s_sum, mysum);
    atomicAdd(&s_cnt, myc);
    __syncthreads();
    if (tid == 0) {
        int c = s_cnt;
        if (c < 1) c = 1;
        out[0] = -s_sum / (float)c;
    }
}

extern "C" void kernel_launch(void* const* d_in, const int* in_sizes, int n_in,
                              void* d_out, int out_size, void* d_ws, size_t ws_size,
                              hipStream_t stream) {
    const float* probas   = (const float*)d_in[0];
    const float* clusters = (const float*)d_in[1];
    const int*   edges    = (const int*)d_in[2];
    const int*   keypts   = (const int*)d_in[3];
    float* out = (float*)d_out;

    char* ws = (char*)d_ws;
    int*      clst     = (int*)(ws + 0);
    uint32_t* header   = (uint32_t*)(ws + 8192);
    int*      anchor   = (int*)(ws + 8256);
    float*    bc       = (float*)(ws + 41024);
    int*      pos_list = (int*)(ws + 73792);
    int*      neg_list = (int*)(ws + 106560);
    Cand*     cand     = (Cand*)(ws + 139328);
    size_t cap_sz = (ws_size > 139328) ? (ws_size - 139328) / sizeof(Cand) : 0;
    if (cap_sz > (size_t)(1 << 18)) cap_sz = (size_t)(1 << 18);
    int cap = (int)cap_sz;

    k_prep <<<1, 256, 0, stream>>>(clusters, keypts, clst, header);
    k_edges<<<E_CONST / 256, 256, 0, stream>>>(clusters, edges, clst, header, anchor, bc, pos_list, neg_list);
    k_pairs<<<1024, 256, 0, stream>>>(anchor, bc, pos_list, neg_list, header, cand, cap);
    k_topk <<<1, 256, 0, stream>>>(probas, header, cand, cap, out);
}

// Round 2
// 68.568 us; speedup vs baseline: 5.6456x; 5.6456x over previous
//
#include <hip/hip_runtime.h>
#include <stdint.h>

// TripletLoss on MI355X. E=8192, N=2048, K=8, L=16, top-400 of Gumbel-perturbed logw.
// Round 2: anchor-bucketed pair enumeration (O(E*deg) not O(n_pos*n_neg)),
// per-block candidate compaction (1 global atomic per block), 4-pass radix top-k.

#define E_CONST 8192
#define N_CONST 2048
#define K_CONST 8
#define L_CONST 16
#define MAXS 400
#define EPS_F 1e-9f
#define STAGE 6144  // per-block candidate staging (48KB LDS)

struct Cand { float val; uint32_t pack; };

// ---- threefry2x32 with key = jax.random.key(42), partitionable path ----
__device__ __forceinline__ uint2 threefry2x32_42(uint32_t x0, uint32_t x1) {
    const uint32_t ks0 = 0u, ks1 = 42u;
    const uint32_t ks2 = ks0 ^ ks1 ^ 0x1BD11BDAu;
    const uint32_t ks[3] = {ks0, ks1, ks2};
    const int R[2][4] = {{13, 15, 26, 6}, {17, 29, 16, 24}};
    x0 += ks0; x1 += ks1;
#pragma unroll
    for (int g = 0; g < 5; ++g) {
        const int* r = R[g & 1];
#pragma unroll
        for (int q = 0; q < 4; ++q) {
            x0 += x1;
            x1 = (x1 << r[q]) | (x1 >> (32 - r[q]));
            x1 ^= x0;
        }
        x0 += ks[(g + 1) % 3];
        x1 += ks[(g + 2) % 3] + (uint32_t)(g + 1);
    }
    return make_uint2(x0, x1);
}

__device__ __forceinline__ float gumbel_at(uint32_t idx) {
    uint2 o = threefry2x32_42(0u, idx);
    uint32_t bits = o.x ^ o.y;
    float u = __uint_as_float((bits >> 9) | 0x3F800000u) - 1.0f;
    return -logf(-logf(u + EPS_F) + EPS_F);
}

__device__ __forceinline__ int row_argmax(const float* __restrict__ row) {
    float best = row[0]; int bi = 0;
#pragma unroll
    for (int k = 1; k < K_CONST; ++k) {
        float v = row[k];
        if (v > best) { best = v; bi = k; }  // first-max == jnp.argmax
    }
    return bi;
}

__device__ __forceinline__ uint32_t sortable_key(float f) {
    uint32_t b = __float_as_uint(f);
    return (b & 0x80000000u) ? ~b : (b | 0x80000000u);
}

// ---- kernel 1: per-edge prep + anchor linked lists (head pre-set to -1) ----
__global__ void k_edges(const float* __restrict__ clusters, const int* __restrict__ edges,
                        const int* __restrict__ keypts,
                        int* __restrict__ head, int* __restrict__ next,
                        int* __restrict__ anchor, float* __restrict__ bc,
                        unsigned char* __restrict__ flags) {
    __shared__ uint32_t s_mask;
    int tid = threadIdx.x;
    if (tid == 0) s_mask = 0;
    __syncthreads();
    if (tid < L_CONST) {
        int n = keypts[tid];
        int bi = row_argmax(clusters + n * K_CONST);
        atomicOr(&s_mask, 1u << bi);
    }
    __syncthreads();
    uint32_t m = s_mask;

    int e = blockIdx.x * blockDim.x + tid;  // grid sized exactly E
    int e0 = edges[2 * e], e1 = edges[2 * e + 1];
    const float* r0 = clusters + e0 * K_CONST;
    const float* r1 = clusters + e1 * K_CONST;
    int c0 = row_argmax(r0);
    int c1 = row_argmax(r1);
    float s = 0.f;
#pragma unroll
    for (int k = 0; k < K_CONST; ++k) s += sqrtf(r0[k] * r1[k]);  // sequential, matches ref

    anchor[e] = e0;
    bc[e] = s;
    bool sel = ((m >> c0) & 1u) | ((m >> c1) & 1u);
    unsigned char f = 0;
    if (sel) f = (c0 == c1) ? 1 : 2;  // 1=pos, 2=neg
    flags[e] = f;
    int old = atomicExch(&head[e0], e);
    next[e] = old;
}

// ---- kernel 2: enumerate same-anchor (pos,neg) pairs, compact per block ----
__global__ void k_cand(const int* __restrict__ head, const int* __restrict__ next,
                       const int* __restrict__ anchor, const float* __restrict__ bc,
                       const unsigned char* __restrict__ flags,
                       uint32_t* __restrict__ count, Cand* __restrict__ cand, int cap) {
    __shared__ int s_cnt;
    __shared__ int s_base;
    __shared__ Cand s_stage[STAGE];
    if (threadIdx.x == 0) s_cnt = 0;
    __syncthreads();

    int e = blockIdx.x * blockDim.x + threadIdx.x;  // grid sized exactly E
    if (flags[e] == 1) {  // pos edge
        float bi = bc[e];
        int a = anchor[e];
        for (int j = head[a]; j >= 0; j = next[j]) {
            if (flags[j] != 2) continue;  // need neg edge (j != e automatically)
            float w = 1.0f - 0.5f * (bi + bc[j]);
            if (!(w > 0.0f)) continue;  // invalid or w<=0 -> logw = -inf, never in top-k
            float val = logf(fmaxf(w, EPS_F)) + gumbel_at((uint32_t)e * E_CONST + (uint32_t)j);
            uint32_t pk = ((uint32_t)e << 16) | (uint32_t)j;
            int s = atomicAdd(&s_cnt, 1);
            if (s < STAGE) {
                s_stage[s].val = val; s_stage[s].pack = pk;
            } else {  // overflow fallback (statistically never)
                int g = atomicAdd((int*)count, 1);
                if (g < cap) { cand[g].val = val; cand[g].pack = pk; }
            }
        }
    }
    __syncthreads();
    int n = s_cnt; if (n > STAGE) n = STAGE;
    if (threadIdx.x == 0) s_base = atomicAdd((int*)count, n);  // 1 global atomic / block
    __syncthreads();
    int base = s_base;
    for (int t = threadIdx.x; t < n; t += blockDim.x) {
        int g = base + t;
        if (g < cap) cand[g] = s_stage[t];
    }
}

// ---- kernel 3: 4-pass radix-histogram threshold + reduction ----
__global__ void k_topk(const float* __restrict__ probas, const uint32_t* __restrict__ count,
                       const Cand* __restrict__ cand, int cap, float* __restrict__ out) {
    __shared__ int hist[256];
    __shared__ uint32_t s_prefix;
    __shared__ int s_target;
    __shared__ float s_sum;
    __shared__ int s_scnt;

    int M = (int)count[0]; if (M > cap) M = cap;
    int tid = threadIdx.x;

    uint32_t thr = 0;
    if (M > MAXS) {
        if (tid == 0) { s_prefix = 0; s_target = MAXS; }
        __syncthreads();
        for (int pass = 0; pass < 4; ++pass) {
            int shift = 24 - 8 * pass;
            for (int b = tid; b < 256; b += blockDim.x) hist[b] = 0;
            __syncthreads();
            uint32_t pfx = s_prefix;
            for (int t = tid; t < M; t += blockDim.x) {
                uint32_t k = sortable_key(cand[t].val);
                if (pass == 0 || (k >> (shift + 8)) == pfx)
                    atomicAdd(&hist[(k >> shift) & 255], 1);
            }
            __syncthreads();
            if (tid == 0) {
                int tgt = s_target;
                int b = 255;
                for (; b > 0; --b) {
                    if (tgt - hist[b] <= 0) break;
                    tgt -= hist[b];
                }
                s_prefix = (pfx << 8) | (uint32_t)b;
                s_target = tgt;
            }
            __syncthreads();
        }
        thr = s_prefix;  // exact sortable key of the 400th-largest value
    }

    if (tid == 0) { s_sum = 0.f; s_scnt = 0; }
    __syncthreads();
    float mysum = 0.f;
    int myc = 0;
    for (int t = tid; t < M; t += blockDim.x) {
        if (sortable_key(cand[t].val) >= thr) {
            uint32_t pk = cand[t].pack;
            int i = (int)(pk >> 16), j = (int)(pk & 0xFFFFu);
            float pi = probas[i], pj = probas[j];
            mysum += logf(pi / (pi + pj));
            myc++;
        }
    }
    atomicAdd(&s_sum, mysum);
    atomicAdd(&s_scnt, myc);
    __syncthreads();
    if (tid == 0) {
        int c = s_scnt; if (c < 1) c = 1;
        out[0] = -s_sum / (float)c;
    }
}

extern "C" void kernel_launch(void* const* d_in, const int* in_sizes, int n_in,
                              void* d_out, int out_size, void* d_ws, size_t ws_size,
                              hipStream_t stream) {
    const float* probas   = (const float*)d_in[0];
    const float* clusters = (const float*)d_in[1];
    const int*   edges    = (const int*)d_in[2];
    const int*   keypts   = (const int*)d_in[3];
    float* out = (float*)d_out;

    char* ws = (char*)d_ws;
    int*           head   = (int*)(ws + 0);        // N*4      = 8192
    int*           next   = (int*)(ws + 8192);     // E*4      = 32768
    int*           anchor = (int*)(ws + 40960);    // E*4      = 32768
    float*         bc     = (float*)(ws + 73728);  // E*4      = 32768
    unsigned char* flags  = (unsigned char*)(ws + 106496);  // E = 8192
    uint32_t*      count  = (uint32_t*)(ws + 114688);       // 64B pad
    Cand*          cand   = (Cand*)(ws + 114752);
    size_t cap_sz = (ws_size > 114752) ? (ws_size - 114752) / sizeof(Cand) : 0;
    if (cap_sz > (size_t)(1 << 18)) cap_sz = (size_t)(1 << 18);
    int cap = (int)cap_sz;

    hipMemsetAsync(head, 0xFF, N_CONST * sizeof(int), stream);  // head = -1
    hipMemsetAsync(count, 0, sizeof(uint32_t), stream);

    k_edges<<<E_CONST / 256, 256, 0, stream>>>(clusters, edges, keypts, head, next, anchor, bc, flags);
    k_cand <<<E_CONST / 256, 256, 0, stream>>>(head, next, anchor, bc, flags, count, cand, cap);
    k_topk <<<1, 1024, 0, stream>>>(probas, count, cand, cap, out);
}